// Round 1
// baseline (492.223 us; speedup 1.0000x reference)
//
#include <hip/hip_runtime.h>
#include <math.h>

#define HH 128
#define WW 128
#define CC 64
#define BB 8
#define OC 64
#define OFFC 18
#define HW (HH*WW)

// ws layout (floats):
//   [0)                offs:   B*18*H*W = 2359296
//   [2359296)          wT_reg: 576*64   = 36864   (wT_reg[kidx*64+o] = w_reg[o*576+kidx])
//   [2396160)          wT_off: 64*18*9  = 10368   (wT_off[(c*18+o)*9+t] = w_off[(o*64+c)*9+t])
#define OFFS_OFF   0
#define WTREG_OFF  2359296
#define WTOFF_OFF  2396160

__global__ __launch_bounds__(256) void transpose_weights_kernel(
    const float* __restrict__ w_reg, const float* __restrict__ w_off,
    float* __restrict__ wT_reg, float* __restrict__ wT_off)
{
    int i = blockIdx.x * 256 + threadIdx.x;
    if (i < 576 * 64) {
        int kidx = i >> 6, o = i & 63;
        wT_reg[i] = w_reg[o * 576 + kidx];
    }
    if (i < CC * OFFC * 9) {
        int t = i % 9;
        int r = i / 9;          // r = c*18 + o
        int o = r % OFFC;
        int c = r / OFFC;
        wT_off[i] = w_off[(o * CC + c) * 9 + t];
    }
}

// One thread per (b,h,w): 3x3 conv over 64 input channels -> 18 offset channels
__global__ __launch_bounds__(256) void offset_conv_kernel(
    const float* __restrict__ x, const float* __restrict__ wT_off,
    const float* __restrict__ b_off, float* __restrict__ offs)
{
    int idx = blockIdx.x * 256 + threadIdx.x;   // over B*H*W = 131072
    int wv = idx & (WW - 1);
    int hv = (idx >> 7) & (HH - 1);
    int bv = idx >> 14;

    float acc[OFFC];
    #pragma unroll
    for (int o = 0; o < OFFC; ++o) acc[o] = b_off[o];

    const float* xb = x + bv * (CC * HW);
    for (int c = 0; c < CC; ++c) {
        const float* xc = xb + c * HW;
        float v[9];
        #pragma unroll
        for (int t = 0; t < 9; ++t) {
            int dy = t / 3 - 1, dx = t % 3 - 1;
            int yy = hv + dy, xx = wv + dx;
            bool ok = (yy >= 0) && (yy < HH) && (xx >= 0) && (xx < WW);
            v[t] = ok ? xc[yy * WW + xx] : 0.0f;
        }
        const float* wc = wT_off + c * (OFFC * 9);   // contiguous, wave-uniform
        #pragma unroll
        for (int o = 0; o < OFFC; ++o) {
            #pragma unroll
            for (int t = 0; t < 9; ++t)
                acc[o] = fmaf(wc[o * 9 + t], v[t], acc[o]);
        }
    }

    float* op = offs + bv * (OFFC * HW) + hv * WW + wv;
    #pragma unroll
    for (int o = 0; o < OFFC; ++o) op[o * HW] = acc[o];
}

// One thread per (b,h,w): deformable sampling + 64-wide output GEMM
__global__ __launch_bounds__(256) void deform_main_kernel(
    const float* __restrict__ x, const float* __restrict__ offs,
    const float* __restrict__ wT_reg, const float* __restrict__ b_reg,
    float* __restrict__ out)
{
    int idx = blockIdx.x * 256 + threadIdx.x;   // over B*H*W
    int wv = idx & (WW - 1);
    int hv = (idx >> 7) & (HH - 1);
    int bv = idx >> 14;

    float acc[OC];
    #pragma unroll
    for (int o = 0; o < OC; ++o) acc[o] = 0.0f;

    const float* xb = x + bv * (CC * HW);
    const float* ob = offs + bv * (OFFC * HW) + hv * WW + wv;
    const float scale = 129.0f / 127.0f;

    for (int k = 0; k < 9; ++k) {
        float offx = ob[(2 * k) * HW];
        float offy = ob[(2 * k + 1) * HW];
        float px = (float)wv + (float)(k % 3 - 1) + offx;
        float py = (float)hv + (float)(k / 3 - 1) + offy;
        float qx = px * scale;
        float qy = py * scale;
        float x0f = floorf(qx), y0f = floorf(qy);
        float wx1 = qx - x0f, wy1 = qy - y0f;
        float wx0 = 1.0f - wx1, wy0 = 1.0f - wy1;
        int ix0 = (int)x0f, iy0 = (int)y0f;
        int ix1 = ix0 + 1, iy1 = iy0 + 1;

        // xp (padded) corner value nonzero iff index in [1,128]; value = x[i-1]
        bool vx0 = (ix0 >= 1) && (ix0 <= WW);
        bool vx1 = (ix1 >= 1) && (ix1 <= WW);
        bool vy0 = (iy0 >= 1) && (iy0 <= HH);
        bool vy1 = (iy1 >= 1) && (iy1 <= HH);
        int jx0 = min(max(ix0 - 1, 0), WW - 1);
        int jx1 = min(max(ix1 - 1, 0), WW - 1);
        int jy0 = min(max(iy0 - 1, 0), HH - 1);
        int jy1 = min(max(iy1 - 1, 0), HH - 1);

        float w00 = wy0 * wx0 * ((vy0 && vx0) ? 1.0f : 0.0f);
        float w01 = wy0 * wx1 * ((vy0 && vx1) ? 1.0f : 0.0f);
        float w10 = wy1 * wx0 * ((vy1 && vx0) ? 1.0f : 0.0f);
        float w11 = wy1 * wx1 * ((vy1 && vx1) ? 1.0f : 0.0f);

        int p00 = jy0 * WW + jx0, p01 = jy0 * WW + jx1;
        int p10 = jy1 * WW + jx0, p11 = jy1 * WW + jx1;

        for (int c = 0; c < CC; ++c) {
            const float* xc = xb + c * HW;
            float s = w00 * xc[p00] + w01 * xc[p01]
                    + w10 * xc[p10] + w11 * xc[p11];
            const float* wr = wT_reg + (c * 9 + k) * 64;   // contiguous, wave-uniform
            #pragma unroll
            for (int o = 0; o < OC; ++o)
                acc[o] = fmaf(wr[o], s, acc[o]);
        }
    }

    float* op = out + bv * (OC * HW) + hv * WW + wv;
    #pragma unroll
    for (int o = 0; o < OC; ++o) op[o * HW] = acc[o] + b_reg[o];
}

extern "C" void kernel_launch(void* const* d_in, const int* in_sizes, int n_in,
                              void* d_out, int out_size, void* d_ws, size_t ws_size,
                              hipStream_t stream) {
    const float* x     = (const float*)d_in[0];
    const float* w_off = (const float*)d_in[1];
    const float* b_off = (const float*)d_in[2];
    const float* w_reg = (const float*)d_in[3];
    const float* b_reg = (const float*)d_in[4];
    float* out = (float*)d_out;
    float* ws  = (float*)d_ws;

    float* offs   = ws + OFFS_OFF;
    float* wT_reg = ws + WTREG_OFF;
    float* wT_off = ws + WTOFF_OFF;

    transpose_weights_kernel<<<144, 256, 0, stream>>>(w_reg, w_off, wT_reg, wT_off);
    offset_conv_kernel<<<512, 256, 0, stream>>>(x, wT_off, b_off, offs);
    deform_main_kernel<<<512, 256, 0, stream>>>(x, offs, wT_reg, b_reg, out);
}